// Round 3
// baseline (188.909 us; speedup 1.0000x reference)
//
#include <hip/hip_runtime.h>
#include <hip/hip_bf16.h>
#include <math.h>

// x: [D=32, N=9216] fp32. 3 iters: w(i,j)=exp(3*<x_i,x_j>),
// x[:,j] <- 0.5*sum_i w*x[:,i]/sum_i w + 0.5*x[:,j]
// Output: [x3][x1][x2][x3].
// bf16 MFMA flash-style; i-split partials to plain stores (no atomics),
// 64-i staging per barrier.

#define D 32
#define NPIX 9216
#define NSPLIT 16            // i-split for grid saturation
#define JB 128               // j per block = 4 waves * 32 j
#define NJB (NPIX / JB)      // 72 j-blocks
#define IPB (NPIX / NSPLIT)  // 576 i per block
#define ICH 64               // i per barrier (2 sub-chunks of 32)
#define XST 56               // LDS row stride (shorts), conflict-free for b128 tile reads
#define WST 56
#define TS  40               // combine transpose tile stride (shorts)

typedef __attribute__((ext_vector_type(8))) short short8;
typedef __attribute__((ext_vector_type(4))) float f32x4;
typedef __attribute__((ext_vector_type(2))) unsigned int u32x2;

#if __has_builtin(__builtin_amdgcn_exp2f)
#define EXP2F __builtin_amdgcn_exp2f
#else
#define EXP2F exp2f
#endif

#define C3 4.32808512266689f   // 3 * log2(e)

__device__ __forceinline__ unsigned pack2_bf16(float a, float b) {
    union { __hip_bfloat162 h2; unsigned u; } c;
    c.h2 = __float22bfloat162_rn(make_float2(a, b));
    return c.u;
}
__device__ __forceinline__ short pack1_bf16(float a) {
    union { __hip_bfloat16 h; unsigned short s; } c;
    c.h = __float2bfloat16(a);
    return (short)c.s;
}

// num_part[bi][d][j] = sum_{i in split bi} w(i,j)*x[d][i]; den_part[bi][j] likewise.
__global__ __launch_bounds__(256) void accum_kernel(
    const short* __restrict__ xb,    // bf16 bits [D][NPIX]
    const short* __restrict__ xbT,   // bf16 bits [NPIX][D]
    float* __restrict__ num_part,    // [NSPLIT][D][NPIX]
    float* __restrict__ den_part)    // [NSPLIT][NPIX]
{
    __shared__ __align__(16) short xiT_s[2][32 * XST];     // [chunk][ii][d]
    __shared__ __align__(16) short xi_s [2][32 * XST];     // [chunk][d][ii]
    __shared__ __align__(16) short w_s[4][2][16 * WST];    // [wave][j-tile][j_local][ii]

    const int t = threadIdx.x;
    const int wid = t >> 6, lane = t & 63, quad = lane >> 4, m = lane & 15;
    const int bj = blockIdx.x % NJB, bi = blockIdx.x / NJB;
    const int j0 = bj * JB + wid * 32;
    const int i0b = bi * IPB;

    // Hoisted QK B-frags (j side): B[k=d][n=j_local], lane: n=m, k=quad*8+e
    short8 bfrag[2];
#pragma unroll
    for (int jt = 0; jt < 2; ++jt)
        bfrag[jt] = *(const short8*)&xbT[(j0 + jt * 16 + m) * D + quad * 8];

    f32x4 acc[2][2] = {};            // [d-tile][j-tile], C-layout
    float dacc[2] = {0.f, 0.f};

    // staging coords
    const int srT = t >> 2,  scT = (t & 3) * 8;            // xbT: 64 rows x 4x8 shorts
    const int srV = t >> 3,  cV = (t & 7) >> 2, qV = ((t & 3)) * 8;  // xb: 32 d x 2 chunk x 4x8

    for (int ic = 0; ic < IPB; ic += ICH) {
        const int i0 = i0b + ic;
        __syncthreads();
        // stage 64 i in both layouts (16B LDS writes, coalesced global reads)
        *(short8*)&xiT_s[srT >> 5][(srT & 31) * XST + scT] =
            *(const short8*)&xbT[(i0 + srT) * D + scT];
        *(short8*)&xi_s[cV][srV * XST + qV] =
            *(const short8*)&xb[srV * NPIX + i0 + cV * 32 + qV];
        __syncthreads();

#pragma unroll
        for (int h = 0; h < 2; ++h) {
            // A-frags for this 32-i sub-chunk
            short8 aT[2], aV[2];
#pragma unroll
            for (int it = 0; it < 2; ++it)
                aT[it] = *(const short8*)&xiT_s[h][(it * 16 + m) * XST + quad * 8];
#pragma unroll
            for (int dt = 0; dt < 2; ++dt)
                aV[dt] = *(const short8*)&xi_s[h][(dt * 16 + m) * XST + quad * 8];

#pragma unroll
            for (int jt = 0; jt < 2; ++jt) {
                f32x4 z = {0.f, 0.f, 0.f, 0.f};
                f32x4 s0 = __builtin_amdgcn_mfma_f32_16x16x32_bf16(aT[0], bfrag[jt], z, 0, 0, 0);
                f32x4 s1 = __builtin_amdgcn_mfma_f32_16x16x32_bf16(aT[1], bfrag[jt], z, 0, 0, 0);

                float w[8];
#pragma unroll
                for (int r = 0; r < 4; ++r) { w[r]     = EXP2F(C3 * s0[r]);
                                              w[4 + r] = EXP2F(C3 * s1[r]); }
#pragma unroll
                for (int r = 0; r < 8; ++r) dacc[jt] += w[r];

                // C-layout -> [j][i] LDS: lane holds w[i=it*16+quad*4+r][j=m]
                u32x2 p0, p1;
                p0.x = pack2_bf16(w[0], w[1]); p0.y = pack2_bf16(w[2], w[3]);
                p1.x = pack2_bf16(w[4], w[5]); p1.y = pack2_bf16(w[6], w[7]);
                *(u32x2*)&w_s[wid][jt][m * WST +      quad * 4] = p0;
                *(u32x2*)&w_s[wid][jt][m * WST + 16 + quad * 4] = p1;

                // B-frag of w: B[k=ii][n=j_local]
                short8 wb = *(const short8*)&w_s[wid][jt][m * WST + quad * 8];

                acc[0][jt] = __builtin_amdgcn_mfma_f32_16x16x32_bf16(aV[0], wb, acc[0][jt], 0, 0, 0);
                acc[1][jt] = __builtin_amdgcn_mfma_f32_16x16x32_bf16(aV[1], wb, acc[1][jt], 0, 0, 0);
            }
        }
    }

    // Plain coalesced stores of this split's partials (each element written once).
    float* np = num_part + (size_t)bi * D * NPIX;
#pragma unroll
    for (int dt = 0; dt < 2; ++dt)
#pragma unroll
        for (int jt = 0; jt < 2; ++jt)
#pragma unroll
            for (int r = 0; r < 4; ++r)
                np[(dt * 16 + quad * 4 + r) * NPIX + j0 + jt * 16 + m] = acc[dt][jt][r];
#pragma unroll
    for (int jt = 0; jt < 2; ++jt) {
        float v = dacc[jt];
        v += __shfl_xor(v, 16, 64);
        v += __shfl_xor(v, 32, 64);
        if (quad == 0) den_part[bi * NPIX + j0 + jt * 16 + m] = v;
    }
}

// v = 0.5*(sum_s num_part)/(sum_s den_part) + 0.5*xin (or v=xin if !do_ms).
// Writes xout/xfinal (fp32), xb (bf16 [D][N]), xbT (bf16 [N][D] via LDS transpose).
__global__ __launch_bounds__(256) void combine_kernel(
    const float* __restrict__ xin,
    const float* __restrict__ num_part, const float* __restrict__ den_part,
    float* __restrict__ xout, float* __restrict__ xfinal,
    short* __restrict__ xb, short* __restrict__ xbT, int do_ms)
{
    __shared__ __align__(16) short tile[64 * TS];   // [i_local][d]
    const int t = threadIdx.x;
    const int il = t & 63, q = t >> 6;
    const int i = blockIdx.x * 64 + il;
    const int d0 = q * 8;

    float inv = 0.f;
    if (do_ms) {
        float den = 0.f;
#pragma unroll
        for (int s = 0; s < NSPLIT; ++s) den += den_part[s * NPIX + i];
        inv = 0.5f / den;
    }

#pragma unroll
    for (int dd = 0; dd < 8; ++dd) {
        const int d = d0 + dd;
        const int idx = d * NPIX + i;
        float v;
        if (do_ms) {
            float nm = 0.f;
#pragma unroll
            for (int s = 0; s < NSPLIT; ++s) nm += num_part[(s * D + d) * NPIX + i];
            v = nm * inv + 0.5f * xin[idx];
            xout[idx] = v;
            if (xfinal) xfinal[idx] = v;
        } else {
            v = xin[idx];
        }
        short b = pack1_bf16(v);
        xb[idx] = b;
        tile[il * TS + d] = b;
    }
    __syncthreads();
    *(short8*)&xbT[i * D + d0] = *(const short8*)&tile[il * TS + d0];
}

extern "C" void kernel_launch(void* const* d_in, const int* in_sizes, int n_in,
                              void* d_out, int out_size, void* d_ws, size_t ws_size,
                              hipStream_t stream)
{
    const float* x0 = (const float*)d_in[0];
    float* out = (float*)d_out;              // [x3][x1][x2][x3]
    const size_t slot = (size_t)D * NPIX;

    float* num_part = (float*)d_ws;                        // NSPLIT*D*NPIX f32 (18.9 MB)
    float* den_part = num_part + (size_t)NSPLIT * slot;    // NSPLIT*NPIX f32
    short* xb  = (short*)(den_part + (size_t)NSPLIT * NPIX);
    short* xbT = xb + slot;

    // convert x0 -> xb/xbT
    combine_kernel<<<dim3(NPIX / 64), dim3(256), 0, stream>>>(
        x0, nullptr, nullptr, nullptr, nullptr, xb, xbT, 0);

    for (int t = 0; t < 3; ++t) {
        accum_kernel<<<dim3(NJB * NSPLIT), dim3(256), 0, stream>>>(
            xb, xbT, num_part, den_part);
        const float* xin = (t == 0) ? x0 : (out + (size_t)t * slot);
        combine_kernel<<<dim3(NPIX / 64), dim3(256), 0, stream>>>(
            xin, num_part, den_part, out + (size_t)(t + 1) * slot,
            (t == 2) ? out : nullptr, xb, xbT, 1);
    }
}

// Round 4
// 173.231 us; speedup vs baseline: 1.0905x; 1.0905x over previous
//
#include <hip/hip_runtime.h>
#include <hip/hip_bf16.h>
#include <math.h>

// x: [D=32, N=9216] fp32. 3 iters: w(i,j)=exp(3*<x_i,x_j>),
// x[:,j] <- 0.5*sum_i w*x[:,i]/sum_i w + 0.5*x[:,j]
// Output: [x3][x1][x2][x3].
// bf16 MFMA flash-style, TRANSPOSE-FREE: QK A-rows are bit-permuted so the
// S tiles land in registers already matching the PV B-fragment layout
// (w = exp(S) packed in-register; no LDS round-trip, no lgkmcnt hazards).

#define D 32
#define NPIX 9216
#define NSPLIT 16            // i-split; grid = 36*16 = 576 blocks (1 resident pass)
#define JB 256               // j per block = 4 waves * 64 j
#define NJB (NPIX / JB)      // 36
#define IPB (NPIX / NSPLIT)  // 576 i per block
#define ICH 64               // i staged per barrier (2 sub-chunks of 32)
#define XST 56               // LDS row stride (shorts)
#define TS  40               // combine transpose tile stride (shorts)

typedef __attribute__((ext_vector_type(8))) short short8;
typedef __attribute__((ext_vector_type(4))) short short4v;
typedef __attribute__((ext_vector_type(4))) float f32x4;

#if __has_builtin(__builtin_amdgcn_exp2f)
#define EXP2F __builtin_amdgcn_exp2f
#else
#define EXP2F exp2f
#endif

#define C3 4.32808512266689f   // 3 * log2(e)

__device__ __forceinline__ unsigned pack2_bf16(float a, float b) {
    union { __hip_bfloat162 h2; unsigned u; } c;
    c.h2 = __float22bfloat162_rn(make_float2(a, b));
    return c.u;
}
__device__ __forceinline__ short pack1_bf16(float a) {
    union { __hip_bfloat16 h; unsigned short s; } c;
    c.h = __float2bfloat16(a);
    return (short)c.s;
}

// num_part[bi][d][j] = sum_{i in split bi} w(i,j)*x[d][i]; den_part[bi][j] likewise.
__global__ __launch_bounds__(256, 2) void accum_kernel(
    const short* __restrict__ xb,    // bf16 bits [D][NPIX]
    const short* __restrict__ xbT,   // bf16 bits [NPIX][D]
    float* __restrict__ num_part,    // [NSPLIT][D][NPIX]
    float* __restrict__ den_part)    // [NSPLIT][NPIX]
{
    // xiT_s rows are sigma-permuted: x_i stored at row sigma(i) so that
    // QK mfma on rows m / 16+m yields C regs holding i = quad*8+{0..3} / {4..7}
    // == exactly the PV B-fragment's k distribution.
    __shared__ __align__(16) short xiT_s[2][32 * XST];   // [chunk][sigma(i)][d]
    __shared__ __align__(16) short xi_s [2][32 * XST];   // [chunk][d][i]

    const int t = threadIdx.x;
    const int wid = t >> 6, lane = t & 63, quad = lane >> 4, m = lane & 15;
    const int bj = blockIdx.x % NJB, bi = blockIdx.x / NJB;
    const int j0 = bj * JB + wid * 64;
    const int i0b = bi * IPB;

    // Hoisted QK B-frags (j side): B[k=d][n=j_local]; lane: n=m, k=quad*8+e
    short8 bfrag[4];
#pragma unroll
    for (int jt = 0; jt < 4; ++jt)
        bfrag[jt] = *(const short8*)&xbT[(size_t)(j0 + jt * 16 + m) * D + quad * 8];

    f32x4 acc[2][4] = {};                       // [d-tile][j-tile], C-layout
    float dacc[4] = {0.f, 0.f, 0.f, 0.f};

    // staging coords
    const int srT = t >> 2, hT = srT >> 5, ilT = srT & 31, cT = (t & 3) * 8;
    const int sgm = ((ilT & 4) << 2) + ((ilT >> 3) << 2) + (ilT & 3);  // sigma(i)
    const int dV = t >> 3, cV = (t & 7) >> 2, qV = (t & 3) * 8;

    for (int ic = 0; ic < IPB; ic += ICH) {
        const int i0 = i0b + ic;
        __syncthreads();
        *(short8*)&xiT_s[hT][sgm * XST + cT] =
            *(const short8*)&xbT[(size_t)(i0 + srT) * D + cT];
        *(short8*)&xi_s[cV][dV * XST + qV] =
            *(const short8*)&xb[dV * NPIX + i0 + cV * 32 + qV];
        __syncthreads();

#pragma unroll
        for (int h = 0; h < 2; ++h) {
            // QK A-frags (permuted rows m / 16+m) and PV A-frags (d rows)
            short8 aT0 = *(const short8*)&xiT_s[h][m * XST + quad * 8];
            short8 aT1 = *(const short8*)&xiT_s[h][(16 + m) * XST + quad * 8];
            short8 aV0 = *(const short8*)&xi_s[h][m * XST + quad * 8];
            short8 aV1 = *(const short8*)&xi_s[h][(16 + m) * XST + quad * 8];

#pragma unroll
            for (int jt = 0; jt < 4; ++jt) {
                f32x4 z = {0.f, 0.f, 0.f, 0.f};
                // s0 regs r: S[i=quad*8+r][j=m]; s1 regs r: S[i=quad*8+4+r][j=m]
                f32x4 s0 = __builtin_amdgcn_mfma_f32_16x16x32_bf16(aT0, bfrag[jt], z, 0, 0, 0);
                f32x4 s1 = __builtin_amdgcn_mfma_f32_16x16x32_bf16(aT1, bfrag[jt], z, 0, 0, 0);

                float w[8];
#pragma unroll
                for (int r = 0; r < 4; ++r) { w[r]     = EXP2F(C3 * s0[r]);
                                              w[4 + r] = EXP2F(C3 * s1[r]); }
#pragma unroll
                for (int r = 0; r < 8; ++r) dacc[jt] += w[r];

                // In-register B-frag of w: element e = i-offset quad*8+e
                union { short8 s; unsigned u[4]; } wb;
                wb.u[0] = pack2_bf16(w[0], w[1]);
                wb.u[1] = pack2_bf16(w[2], w[3]);
                wb.u[2] = pack2_bf16(w[4], w[5]);
                wb.u[3] = pack2_bf16(w[6], w[7]);

                // num[d][j] += x[d][i] * w[i][j]  (M=d, N=j, K=i=32)
                acc[0][jt] = __builtin_amdgcn_mfma_f32_16x16x32_bf16(aV0, wb.s, acc[0][jt], 0, 0, 0);
                acc[1][jt] = __builtin_amdgcn_mfma_f32_16x16x32_bf16(aV1, wb.s, acc[1][jt], 0, 0, 0);
            }
        }
    }

    // Plain coalesced stores of this split's partials.
    float* np = num_part + (size_t)bi * D * NPIX;
#pragma unroll
    for (int dt = 0; dt < 2; ++dt)
#pragma unroll
        for (int jt = 0; jt < 4; ++jt)
#pragma unroll
            for (int r = 0; r < 4; ++r)
                np[(dt * 16 + quad * 4 + r) * NPIX + j0 + jt * 16 + m] = acc[dt][jt][r];
#pragma unroll
    for (int jt = 0; jt < 4; ++jt) {
        float v = dacc[jt];
        v += __shfl_xor(v, 16, 64);
        v += __shfl_xor(v, 32, 64);
        if (quad == 0) den_part[bi * NPIX + j0 + jt * 16 + m] = v;
    }
}

// v = 0.5*(sum_s num_part)/(sum_s den_part) + 0.5*xin (or v=xin if !do_ms).
// Writes xout/xfinal (fp32), xb (bf16 [D][N]), xbT (bf16 [N][D] via LDS transpose).
// 288 blocks x 32 i; thread t: i=(t&31), d = (t>>5)*4 .. +3.
__global__ __launch_bounds__(256) void combine_kernel(
    const float* __restrict__ xin,
    const float* __restrict__ num_part, const float* __restrict__ den_part,
    float* __restrict__ xout, float* __restrict__ xfinal,
    short* __restrict__ xb, short* __restrict__ xbT, int do_ms)
{
    __shared__ __align__(16) short tile[32 * TS];   // [i_local][d]
    const int t = threadIdx.x;
    const int il = t & 31, q = t >> 5;
    const int i = blockIdx.x * 32 + il;
    const int d0 = q * 4;

    float inv = 0.f;
    if (do_ms) {
        float den = 0.f;
#pragma unroll
        for (int s = 0; s < NSPLIT; ++s) den += den_part[s * NPIX + i];
        inv = 0.5f / den;
    }

#pragma unroll
    for (int dd = 0; dd < 4; ++dd) {
        const int d = d0 + dd;
        const int idx = d * NPIX + i;
        float v;
        if (do_ms) {
            float nm = 0.f;
#pragma unroll
            for (int s = 0; s < NSPLIT; ++s) nm += num_part[(s * D + d) * NPIX + i];
            v = nm * inv + 0.5f * xin[idx];
            xout[idx] = v;
            if (xfinal) xfinal[idx] = v;
        } else {
            v = xin[idx];
        }
        short b = pack1_bf16(v);
        xb[idx] = b;
        tile[il * TS + d] = b;
    }
    __syncthreads();
    // xbT rows: thread t writes 4 shorts (8 B) at xbT[i2][dc..dc+3]
    const int i2 = t >> 3, dc = (t & 7) * 4;
    *(short4v*)&xbT[(blockIdx.x * 32 + i2) * D + dc] =
        *(const short4v*)&tile[i2 * TS + dc];
}

extern "C" void kernel_launch(void* const* d_in, const int* in_sizes, int n_in,
                              void* d_out, int out_size, void* d_ws, size_t ws_size,
                              hipStream_t stream)
{
    const float* x0 = (const float*)d_in[0];
    float* out = (float*)d_out;              // [x3][x1][x2][x3]
    const size_t slot = (size_t)D * NPIX;

    float* num_part = (float*)d_ws;                        // NSPLIT*D*NPIX f32
    float* den_part = num_part + (size_t)NSPLIT * slot;    // NSPLIT*NPIX f32
    short* xb  = (short*)(den_part + (size_t)NSPLIT * NPIX);
    short* xbT = xb + slot;

    // convert x0 -> xb/xbT
    combine_kernel<<<dim3(NPIX / 32), dim3(256), 0, stream>>>(
        x0, nullptr, nullptr, nullptr, nullptr, xb, xbT, 0);

    for (int t = 0; t < 3; ++t) {
        accum_kernel<<<dim3(NJB * NSPLIT), dim3(256), 0, stream>>>(
            xb, xbT, num_part, den_part);
        const float* xin = (t == 0) ? x0 : (out + (size_t)t * slot);
        combine_kernel<<<dim3(NPIX / 32), dim3(256), 0, stream>>>(
            xin, num_part, den_part, out + (size_t)(t + 1) * slot,
            (t == 2) ? out : nullptr, xb, xbT, 1);
    }
}